// Round 1
// baseline (522.373 us; speedup 1.0000x reference)
//
#include <hip/hip_runtime.h>

typedef _Float16 half8 __attribute__((ext_vector_type(8)));
typedef _Float16 half4 __attribute__((ext_vector_type(4)));
typedef float    floatx16 __attribute__((ext_vector_type(16)));

#define MFMA(a, b, c) __builtin_amdgcn_mfma_f32_32x32x16_f16((a), (b), (c), 0, 0, 0)

constexpr int NB = 32, NC = 256, NL = 1024, MI = 32, BJ = 32;
constexpr int NIT = NL / BJ;   // 32
constexpr int PSP = 36;        // pS row pitch (floats): float4-aligned, bank-rotating

// LDS byte offsets (total 53632 -> 3 blocks/CU)
constexpr int OFF_V    = 0;        // vF  f16 [8 ct][2 ksj][64 ls][8 t] = 16384 (swizzled granules)
constexpr int OFF_S    = 16384;    // sF  same = 16384
constexpr int OFF_PS   = 32768;    // pS  f32 [4 w][32 i][36] = 18432
constexpr int OFF_PB   = 51200;    // pB  f16 [2 ksj][64 ls][8 t] = 2048
constexpr int OFF_ROWS = 53248;    // m/l/a rows 3*32*4 = 384
constexpr int SMEM_B   = 53632;

// Granule swizzle: XOR the two "j-chunk" bits (granule bits 5-6) into bits 1-2 so the
// 4 jc-variants of one c-row land in different bank quads. Applied on write AND read.
__device__ __forceinline__ int swz(int g) { return g ^ (((g >> 5) & 3) << 1); }

__global__ __launch_bounds__(256, 3)
void att_mfma3(const float* __restrict__ q,
               const float* __restrict__ kk,
               const float* __restrict__ v,
               const float* __restrict__ sd,
               const float* __restrict__ bt,
               const int* __restrict__ ri,
               float* __restrict__ out)
{
    __shared__ __align__(16) char smem[SMEM_B];
    _Float16* vH   = (_Float16*)(smem + OFF_V);
    _Float16* sH   = (_Float16*)(smem + OFF_S);
    float*    pS   = (float*)(smem + OFF_PS);
    _Float16* pB   = (_Float16*)(smem + OFF_PB);
    float*    mrow = (float*)(smem + OFF_ROWS);
    float*    lrow = mrow + 32;
    float*    arow = mrow + 64;

    const int tid  = threadIdx.x;
    const int lane = tid & 63;
    const int wv   = tid >> 6;

    // XCD-locality swizzle: one batch's 32 i-blocks cluster on one XCD.
    const int bid = blockIdx.x;
    const int b   = (bid & 7) + ((bid >> 8) << 3);
    const int ib  = (bid >> 3) & 31;
    const int i0  = ib * MI;

    const float* kbase = kk + (size_t)b * NC * NL;
    const float* vbase = v  + (size_t)b * NC * NL;
    const float* sbase = sd + (size_t)b * NC * NL;

    // ---- Q A-fragments (hi/lo fp16). Wave wv owns ks = wv*4 .. wv*4+3 (channels wv*64..wv*64+63)
    half8 qhi[4], qlo[4];
    {
        const float* qb = q + (size_t)b * NC * NL + i0 + (lane & 31);
        #pragma unroll
        for (int kq = 0; kq < 4; ++kq) {
            const int c0 = (wv * 4 + kq) * 16 + (lane >> 5) * 8;
            #pragma unroll
            for (int t = 0; t < 8; ++t) {
                float x = qb[(size_t)(c0 + t) * NL];
                _Float16 h = (_Float16)x;
                qhi[kq][t] = h;
                qlo[kq][t] = (_Float16)(x - (float)h);
            }
        }
    }
    if (tid < 32) { mrow[tid] = -1e30f; lrow[tid] = 0.0f; arow[tid] = 1.0f; }

    // ---- staging geometry (V/SD): coalesced global reads, swizzled conflict-free b128 writes
    int co[4], swg[4];
    #pragma unroll
    for (int r = 0; r < 4; ++r) {
        const int c = (tid >> 2) + r * 64, jc = tid & 3;
        co[r] = c * NL + jc * 8;
        const int gr = ((c >> 5) * 2 + (jc >> 1)) * 64 + (jc & 1) * 32 + (c & 31);
        swg[r] = swz(gr) * 8;
    }
    // PV read offsets (half units), same swizzle
    int gA[2][2];
    #pragma unroll
    for (int d = 0; d < 2; ++d)
        #pragma unroll
        for (int ksj = 0; ksj < 2; ++ksj)
            gA[d][ksj] = swz(((wv * 2 + d) * 2 + ksj) * 64 + lane) * 8;

    floatx16 aV[2], aS[2];
    #pragma unroll
    for (int d = 0; d < 2; ++d)
        #pragma unroll
        for (int r = 0; r < 16; ++r) { aV[d][r] = 0.f; aS[d][r] = 0.f; }

    auto pv_step = [&]() {
        const float al = arow[lane & 31];
        if (!__all(al == 1.0f)) {   // exact: skip is bitwise-identical when max unchanged
            #pragma unroll
            for (int d = 0; d < 2; ++d)
                #pragma unroll
                for (int r = 0; r < 16; ++r) { aV[d][r] *= al; aS[d][r] *= al; }
        }
        half8 pb0 = *(const half8*)(pB + lane * 8);
        half8 pb1 = *(const half8*)(pB + (64 + lane) * 8);
        #pragma unroll
        for (int d = 0; d < 2; ++d) {
            half8 a0 = *(const half8*)(vH + gA[d][0]);
            half8 a1 = *(const half8*)(vH + gA[d][1]);
            aV[d] = MFMA(a0, pb0, aV[d]);
            aV[d] = MFMA(a1, pb1, aV[d]);
            half8 b0 = *(const half8*)(sH + gA[d][0]);
            half8 b1 = *(const half8*)(sH + gA[d][1]);
            aS[d] = MFMA(b0, pb0, aS[d]);
            aS[d] = MFMA(b1, pb1, aS[d]);
        }
    };

    for (int it = 0; it < NIT; ++it) {
        const int j0 = it * BJ;

        // ---- K fragment loads for THIS tile, direct global->reg (no LDS round-trip).
        // Same coalescing as the old stage_k (2x128B per instr); latency hides under PV.
        float kr[4][8];
        {
            const float* kcol = kbase + j0 + (lane & 31);
            #pragma unroll
            for (int kq = 0; kq < 4; ++kq) {
                const int c0 = (wv * 4 + kq) * 16 + (lane >> 5) * 8;
                #pragma unroll
                for (int t = 0; t < 8; ++t)
                    kr[kq][t] = kcol[(size_t)(c0 + t) * NL];
            }
        }

        // ---- PV(it-1): all waves, 2 c-tiles each ----
        if (it > 0) pv_step();

        // ---- scores(it): ALL 4 waves, quarter-C partials each ----
        {
            floatx16 S;
            #pragma unroll
            for (int r = 0; r < 16; ++r) S[r] = 0.f;
            #pragma unroll
            for (int kq = 0; kq < 4; ++kq) {
                half8 bf;
                #pragma unroll
                for (int t = 0; t < 8; ++t) bf[t] = (_Float16)kr[kq][t];
                S = MFMA(qhi[kq], bf, S);
                S = MFMA(qlo[kq], bf, S);
            }
            float* ps = pS + wv * 32 * PSP + (lane & 31);
            #pragma unroll
            for (int r = 0; r < 16; ++r) {
                const int row = (r & 3) + 8 * (r >> 2) + 4 * (lane >> 5);
                ps[row * PSP] = S[r];
            }
        }
        __syncthreads();   // B1: pS ready; vF/sF/pB old reads done

        // ---- V prefetch into regs (latency hidden under softmax) ----
        float4 va0[4], va1[4];
        #pragma unroll
        for (int r = 0; r < 4; ++r) {
            const float* src = vbase + co[r] + j0;
            va0[r] = *(const float4*)(src);
            va1[r] = *(const float4*)(src + 4);
        }

        // ---- softmax(it): thread (i = tid>>3, s = tid&7) owns 4 cols; sums 4 partials ----
        {
            const int i = tid >> 3, s = tid & 7;
            const int4 r4 = *(const int4*)(ri + (size_t)(i0 + i) * NL + j0 + s * 4);
            const float* p0 = pS + i * PSP + s * 4;
            const float4 f0 = *(const float4*)(p0);
            const float4 f1 = *(const float4*)(p0 + 32 * PSP);
            const float4 f2 = *(const float4*)(p0 + 64 * PSP);
            const float4 f3 = *(const float4*)(p0 + 96 * PSP);
            float sc[4];
            sc[0] = f0.x + f1.x + f2.x + f3.x + bt[r4.x];
            sc[1] = f0.y + f1.y + f2.y + f3.y + bt[r4.y];
            sc[2] = f0.z + f1.z + f2.z + f3.z + bt[r4.z];
            sc[3] = f0.w + f1.w + f2.w + f3.w + bt[r4.w];
            float lm = fmaxf(fmaxf(sc[0], sc[1]), fmaxf(sc[2], sc[3]));
            lm = fmaxf(lm, __shfl_xor(lm, 1));
            lm = fmaxf(lm, __shfl_xor(lm, 2));
            lm = fmaxf(lm, __shfl_xor(lm, 4));
            const float mo = mrow[i];
            const float mn = fmaxf(lm, mo);
            float sum = 0.f;
            half4 ph;
            #pragma unroll
            for (int x = 0; x < 4; ++x) {
                float e = __expf(sc[x] - mn);
                sum += e;
                ph[x] = (_Float16)e;
            }
            sum += __shfl_xor(sum, 1);
            sum += __shfl_xor(sum, 2);
            sum += __shfl_xor(sum, 4);
            // pB frag: B[k=j][n=i], j = 4s..4s+3 -> ksj=s>>2, half=(s>>1)&1, t0=(s&1)*4
            *(half4*)(pB + (((s >> 2) * 64) + ((s >> 1) & 1) * 32 + i) * 8 + (s & 1) * 4) = ph;
            if (s == 0) {
                float al = __expf(mo - mn);   // == 1.0f exactly when mn == mo
                arow[i] = al;
                lrow[i] = lrow[i] * al + sum;
                mrow[i] = mn;
            }
        }

        // ---- V convert + swizzled LDS write ----
        #pragma unroll
        for (int r = 0; r < 4; ++r) {
            half8 h;
            h[0] = (_Float16)va0[r].x; h[1] = (_Float16)va0[r].y;
            h[2] = (_Float16)va0[r].z; h[3] = (_Float16)va0[r].w;
            h[4] = (_Float16)va1[r].x; h[5] = (_Float16)va1[r].y;
            h[6] = (_Float16)va1[r].z; h[7] = (_Float16)va1[r].w;
            *(half8*)(vH + swg[r]) = h;
        }

        // ---- SD load + convert + swizzled write (latency part-hidden under V cvt/write) ----
        float4 sa0[4], sa1[4];
        #pragma unroll
        for (int r = 0; r < 4; ++r) {
            const float* src = sbase + co[r] + j0;
            sa0[r] = *(const float4*)(src);
            sa1[r] = *(const float4*)(src + 4);
        }
        #pragma unroll
        for (int r = 0; r < 4; ++r) {
            half8 h;
            h[0] = (_Float16)sa0[r].x; h[1] = (_Float16)sa0[r].y;
            h[2] = (_Float16)sa0[r].z; h[3] = (_Float16)sa0[r].w;
            h[4] = (_Float16)sa1[r].x; h[5] = (_Float16)sa1[r].y;
            h[6] = (_Float16)sa1[r].z; h[7] = (_Float16)sa1[r].w;
            *(half8*)(sH + swg[r]) = h;
        }
        __syncthreads();   // B2: pB/rows/vF/sF(it) ready
    }

    // ---- drain PV(NIT-1) ----
    pv_step();

    // ---- epilogue: normalize, LDS transpose (scr overlaps dead vF/sF/pS head), coalesced store ----
    const float linv = 1.0f / lrow[lane & 31];
    float* scr = (float*)smem;   // 256*33*4 = 33792 B < OFF_PB
    __syncthreads();
    #pragma unroll
    for (int d = 0; d < 2; ++d) {
        const int ct = wv * 2 + d;
        #pragma unroll
        for (int r = 0; r < 16; ++r) {
            int c = ct * 32 + (r & 3) + 8 * (r >> 2) + 4 * (lane >> 5);
            scr[c * 33 + (lane & 31)] = aV[d][r] * linv;
        }
    }
    __syncthreads();
    {
        float* og = out + ((size_t)b * NC + tid) * NL + i0;
        #pragma unroll
        for (int g = 0; g < 8; ++g) {
            float4 o;
            o.x = scr[tid * 33 + g * 4 + 0];
            o.y = scr[tid * 33 + g * 4 + 1];
            o.z = scr[tid * 33 + g * 4 + 2];
            o.w = scr[tid * 33 + g * 4 + 3];
            *(float4*)(og + g * 4) = o;
        }
    }
    __syncthreads();
    #pragma unroll
    for (int d = 0; d < 2; ++d) {
        const int ct = wv * 2 + d;
        #pragma unroll
        for (int r = 0; r < 16; ++r) {
            int c = ct * 32 + (r & 3) + 8 * (r >> 2) + 4 * (lane >> 5);
            scr[c * 33 + (lane & 31)] = aS[d][r] * linv;
        }
    }
    __syncthreads();
    {
        float* og = out + (size_t)NB * NC * NL + ((size_t)b * NC + tid) * NL + i0;
        #pragma unroll
        for (int g = 0; g < 8; ++g) {
            float4 o;
            o.x = scr[tid * 33 + g * 4 + 0];
            o.y = scr[tid * 33 + g * 4 + 1];
            o.z = scr[tid * 33 + g * 4 + 2];
            o.w = scr[tid * 33 + g * 4 + 3];
            *(float4*)(og + g * 4) = o;
        }
    }
}

extern "C" void kernel_launch(void* const* d_in, const int* in_sizes, int n_in,
                              void* d_out, int out_size, void* d_ws, size_t ws_size,
                              hipStream_t stream)
{
    (void)in_sizes; (void)n_in; (void)d_ws; (void)ws_size; (void)out_size;
    const float* q  = (const float*)d_in[0];
    const float* k  = (const float*)d_in[1];
    const float* v  = (const float*)d_in[2];
    const float* s  = (const float*)d_in[3];
    const float* bt = (const float*)d_in[4];
    const int*   ri = (const int*)d_in[5];
    att_mfma3<<<dim3(NB * (NL / MI)), dim3(256), 0, stream>>>(
        q, k, v, s, bt, ri, (float*)d_out);
}